// Round 1
// baseline (380.000 us; speedup 1.0000x reference)
//
#include <hip/hip_runtime.h>

constexpr int   NGRID = 1024;
constexpr int   BATCH = 2;
constexpr int   NPTS  = 524288;            // P
constexpr float BETA  = 4.71238898038469f; // 1.5*pi
constexpr float PI_F  = 3.14159265358979f;

// i0(x) for x >= 3.75 (Numerical Recipes asymptotic, rel err ~1e-7)
__device__ __forceinline__ float i0f_large(float x) {
    float t = 3.75f / x;
    float p =  0.00392377f;
    p = p * t + -0.01647633f;
    p = p * t +  0.02635537f;
    p = p * t + -0.02057706f;
    p = p * t +  0.00916281f;
    p = p * t + -0.00157565f;
    p = p * t +  0.00225319f;
    p = p * t +  0.01328592f;
    p = p * t +  0.39894228f;
    return __expf(x) * rsqrtf(x) * p;
}

// gh[k] = fh[k] / (i0_1 * i0_2)  placed at FFT-order index (a-256)&1023.
// (1/1024 per-dim window norm cancels the 1/(n1*n2) FFT normalization.)
__global__ __launch_bounds__(256) void deconv_kernel(const float2* __restrict__ fh,
                                                     float2* __restrict__ g) {
    int t  = blockIdx.x * 256 + threadIdx.x;   // 0 .. 512*512-1
    int b  = blockIdx.y;
    int a1 = t >> 9;
    int a2 = t & 511;

    float k1   = (float)(a1 - 256);
    float w1   = (2.0f * PI_F / 1024.0f) * k1;
    float c1   = i0f_large(4.0f * sqrtf(BETA * BETA - w1 * w1));
    float k2   = (float)(a2 - 256);
    float w2   = (2.0f * PI_F / 1024.0f) * k2;
    float c2   = i0f_large(4.0f * sqrtf(BETA * BETA - w2 * w2));
    float inv  = 1.0f / (c1 * c2);

    float2 v = fh[((long)b << 18) + t];
    int i1 = (a1 - 256) & 1023;
    int i2 = (a2 - 256) & 1023;
    g[((long)b << 20) + (i1 << 10) + i2] = make_float2(v.x * inv, v.y * inv);
}

// In-place radix-2 DIF 1024-pt FFT in LDS. Natural-order input, bit-reversed
// output (caller un-reverses on readout). Forward transform: e^{-2pi i}.
__device__ __forceinline__ void fft1024(float2* s) {
    int tid = threadIdx.x;
    for (int k = 9; k >= 0; --k) {
        int half = 1 << k;
        __syncthreads();
        #pragma unroll
        for (int r = 0; r < 2; ++r) {
            int t    = tid + (r << 8);            // 0..511 butterflies
            int j    = t & (half - 1);
            int blk  = t >> k;
            int base = (blk << (k + 1)) + j;
            float2 a = s[base];
            float2 c = s[base + half];
            float2 d = make_float2(a.x - c.x, a.y - c.y);
            float ang = (-PI_F) * (float)j / (float)half; // -2*pi*j/size
            float sw, cw;
            __sincosf(ang, &sw, &cw);
            s[base]        = make_float2(a.x + c.x, a.y + c.y);
            s[base + half] = make_float2(d.x * cw - d.y * sw,
                                         d.x * sw + d.y * cw);
        }
    }
    __syncthreads();
}

__global__ __launch_bounds__(256) void fft_rows(float2* __restrict__ g) {
    __shared__ float2 s[1024];
    int row = blockIdx.x, b = blockIdx.y;
    float2* base = g + ((long)b << 20) + ((long)row << 10);
    int tid = threadIdx.x;
    #pragma unroll
    for (int i = 0; i < 4; ++i) {
        int idx = tid + (i << 8);
        s[idx] = base[idx];
    }
    fft1024(s);
    #pragma unroll
    for (int i = 0; i < 4; ++i) {
        int idx = tid + (i << 8);
        unsigned rev = __brev((unsigned)idx) >> 22;
        base[idx] = s[rev];
    }
}

__global__ __launch_bounds__(256) void fft_cols(float2* __restrict__ g) {
    __shared__ float2 s[1024];
    int col = blockIdx.x, b = blockIdx.y;
    float2* base = g + ((long)b << 20) + col;
    int tid = threadIdx.x;
    #pragma unroll
    for (int i = 0; i < 4; ++i) {
        int idx = tid + (i << 8);
        s[idx] = base[(long)idx << 10];
    }
    fft1024(s);
    #pragma unroll
    for (int i = 0; i < 4; ++i) {
        int idx = tid + (i << 8);
        unsigned rev = __brev((unsigned)idx) >> 22;
        base[(long)idx << 10] = s[rev];
    }
}

// Kaiser-Bessel time-domain window: sinh(BETA*u)/(pi*u), u=sqrt(16-(frac-off)^2)
__global__ __launch_bounds__(256) void gather_kernel(const float2* __restrict__ x,
                                                     const float2* __restrict__ g,
                                                     float2* __restrict__ out) {
    int gid = blockIdx.x * 256 + threadIdx.x;   // 0 .. B*P-1
    int b   = gid >> 19;                        // P = 2^19
    float2 xv = x[gid];

    float w1[8], w2[8];
    int   i1[8], i2[8];

    {
        float xs  = xv.x * 1024.0f;
        float fl  = floorf(xs);
        int   l0  = (int)fl;
        float fr  = xs - fl;
        #pragma unroll
        for (int i = 0; i < 8; ++i) {
            int   off = i - 3;
            float t   = fr - (float)off;
            float u2  = 16.0f - t * t;
            float u   = sqrtf(fmaxf(u2, 1e-12f));
            float z   = BETA * u;
            w1[i] = (u2 > 0.0f) ? (__expf(z) - __expf(-z)) * 0.5f / (PI_F * u) : 0.0f;
            i1[i] = (l0 + off) & 1023;
        }
    }
    {
        float xs  = xv.y * 1024.0f;
        float fl  = floorf(xs);
        int   l0  = (int)fl;
        float fr  = xs - fl;
        #pragma unroll
        for (int i = 0; i < 8; ++i) {
            int   off = i - 3;
            float t   = fr - (float)off;
            float u2  = 16.0f - t * t;
            float u   = sqrtf(fmaxf(u2, 1e-12f));
            float z   = BETA * u;
            w2[i] = (u2 > 0.0f) ? (__expf(z) - __expf(-z)) * 0.5f / (PI_F * u) : 0.0f;
            i2[i] = (l0 + off) & 1023;
        }
    }

    const float2* gb = g + ((long)b << 20);
    float ar = 0.0f, ai = 0.0f;
    #pragma unroll
    for (int i = 0; i < 8; ++i) {
        const float2* rowp = gb + (i1[i] << 10);
        float wi = w1[i];
        #pragma unroll
        for (int j = 0; j < 8; ++j) {
            float2 gv = rowp[i2[j]];
            float  w  = wi * w2[j];
            ar = fmaf(w, gv.x, ar);
            ai = fmaf(w, gv.y, ai);
        }
    }
    out[gid] = make_float2(ar, ai);
}

extern "C" void kernel_launch(void* const* d_in, const int* in_sizes, int n_in,
                              void* d_out, int out_size, void* d_ws, size_t ws_size,
                              hipStream_t stream) {
    const float2* x  = (const float2*)d_in[0];
    const float2* fh = (const float2*)d_in[1];
    float2* g = (float2*)d_ws;   // B x 1024 x 1024 complex = 16 MB

    hipMemsetAsync(d_ws, 0, (size_t)BATCH * NGRID * NGRID * sizeof(float2), stream);

    dim3 blk(256);
    deconv_kernel<<<dim3(1024, BATCH), blk, 0, stream>>>(fh, g);
    fft_rows    <<<dim3(NGRID, BATCH), blk, 0, stream>>>(g);
    fft_cols    <<<dim3(NGRID, BATCH), blk, 0, stream>>>(g);
    gather_kernel<<<dim3((BATCH * NPTS) / 256), blk, 0, stream>>>(x, g, (float2*)d_out);
}